// Round 14
// baseline (339.518 us; speedup 1.0000x reference)
//
#include <hip/hip_runtime.h>
#include <hip/hip_bf16.h>

// ---------------------------------------------------------------------------
// GCN: h1 = relu(gcnconv(x, W1, b1)); h2 = relu(gcnconv(h1, W2, b2));
//      out = h2 @ Wh + bh
// gcnconv(x,W,b)[d] = dinv[d] * ( sum_{e: src->d} hs[src] + hs[d] ) + b
//   where hs = (x@W) * dinv[row],  dinv = rsqrt(indeg + 1)
// CSR build: bucket hist -> bucket scan -> bin-sort -> per-bucket LDS CSR.
// hs bf16 in 4 FEATURE-SLICE arrays (16 feats = 32B/node, 3.2MB each, fits
// XCD L2; sentinel zero row N). k_pull: one wave per (node, slice);
// 4 lanes/edge x 16 edges per wave-load (512B/instr); csr indices read
// directly by consuming lanes (4-lane broadcast) -> ZERO hot-loop shuffles;
// once-per-node shfl_xor reduce epilogue. slice = blockIdx&3 XCD affinity.
// GEMM: MFMA 16x16x32 bf16, XOR-swizzled LDS, fp32 accumulate.
// ---------------------------------------------------------------------------

#define BIN_SHIFT 9
#define BN        (1 << BIN_SHIFT)     // 512 nodes per bucket
#define NB_MAX    256
#define BIN_CHUNK 4096                 // edges per k_bin block

typedef __attribute__((ext_vector_type(8))) short short8v;   // 8 bf16 (4 VGPR)
typedef __attribute__((ext_vector_type(4))) float f32x4;

__device__ __forceinline__ float bf2f(unsigned short u) {
  union { unsigned i; float f; } c; c.i = ((unsigned)u) << 16; return c.f;
}
__device__ __forceinline__ unsigned short f2bf(float f) {
  union { float f; unsigned i; } c; c.f = f;
  unsigned r = c.i + 0x7FFFu + ((c.i >> 16) & 1u);   // RNE
  return (unsigned short)(r >> 16);
}

__global__ __launch_bounds__(256) void k_zero(int* p, int n) {
  int i = blockIdx.x * blockDim.x + threadIdx.x;
  if (i < n) p[i] = 0;
}

// zero the 4 slice sentinel rows hsS[s][N][0..16)
__global__ __launch_bounds__(64) void k_zrow(unsigned short* hsS, int n) {
  int t = threadIdx.x;
  if (t < 64) {
    int s = t >> 4, f = t & 15;
    hsS[((size_t)s * (n + 1) + n) * 16 + f] = 0;
  }
}

// ---- bucket-level histogram (LDS pre-aggregated)
__global__ __launch_bounds__(256) void k_bhist(const int* __restrict__ dst,
                                               int* bhist, int E, int nb) {
  __shared__ int lh[NB_MAX];
  lh[threadIdx.x] = 0;
  __syncthreads();
  for (int i = blockIdx.x * 256 + threadIdx.x; i < E; i += gridDim.x * 256)
    atomicAdd(&lh[dst[i] >> BIN_SHIFT], 1);
  __syncthreads();
  int v = lh[threadIdx.x];
  if (threadIdx.x < nb && v) atomicAdd(&bhist[threadIdx.x], v);
}

// ---- scan bucket counts -> boff[nb+1], gcur
__global__ __launch_bounds__(256) void k_bscan(const int* __restrict__ bhist,
                                               int* boff, int* gcur, int nb, int E) {
  __shared__ int sh[256];
  const int t = threadIdx.x;
  int v = (t < nb) ? bhist[t] : 0;
  sh[t] = v;
  __syncthreads();
  for (int d = 1; d < 256; d <<= 1) {
    int x = (t >= d) ? sh[t - d] : 0;
    __syncthreads();
    sh[t] += x;
    __syncthreads();
  }
  if (t < nb) { int e = sh[t] - v; boff[t] = e; gcur[t] = e; }
  if (t == 0) boff[nb] = E;
}

// ---- split-sort edges into buckets by dst>>BIN_SHIFT (coalesced drain)
__global__ __launch_bounds__(256) void k_bin(
    const int* __restrict__ src, const int* __restrict__ dst,
    int* gcur, int* __restrict__ binned, int E)
{
  __shared__ int  hist[NB_MAX];
  __shared__ int  excl[NB_MAX];
  __shared__ int  lcur[NB_MAX];
  __shared__ int  gbase[NB_MAX];
  __shared__ int2 stage[BIN_CHUNK];

  const int t = threadIdx.x;
  const int base = blockIdx.x * BIN_CHUNK;
  const int m = min(BIN_CHUNK, E - base);

  int2 pr[BIN_CHUNK / 256];
  int nmine = 0;
  #pragma unroll
  for (int i = 0; i < BIN_CHUNK / 256; ++i) {
    int idx = t + 256 * i;
    if (idx < m) {
      pr[i].x = src[base + idx];
      pr[i].y = dst[base + idx];
      nmine = i + 1;
    }
  }

  hist[t] = 0;
  __syncthreads();
  #pragma unroll
  for (int i = 0; i < BIN_CHUNK / 256; ++i)
    if (i < nmine) atomicAdd(&hist[pr[i].y >> BIN_SHIFT], 1);
  __syncthreads();

  const int mycnt = hist[t];
  for (int d = 1; d < 256; d <<= 1) {
    int v = (t >= d) ? hist[t - d] : 0;
    __syncthreads();
    hist[t] += v;
    __syncthreads();
  }
  {
    int e = hist[t] - mycnt;
    excl[t] = e;
    lcur[t] = e;
    gbase[t] = mycnt ? atomicAdd(&gcur[t], mycnt) : 0;
  }
  __syncthreads();

  #pragma unroll
  for (int i = 0; i < BIN_CHUNK / 256; ++i)
    if (i < nmine) {
      int b = pr[i].y >> BIN_SHIFT;
      int p = atomicAdd(&lcur[b], 1);
      stage[p] = pr[i];
    }
  __syncthreads();

  for (int i = t; i < m; i += 256) {
    int2 pp = stage[i];
    int b = pp.y >> BIN_SHIFT;
    binned[gbase[b] + (i - excl[b])] =
        (pp.x << BIN_SHIFT) | (pp.y & (BN - 1));
  }
}

// ---- per-bucket CSR build: degree hist + scan + offs/endo/dinv + scatter
__global__ __launch_bounds__(256) void k_csr(
    const int* __restrict__ binned, const int* __restrict__ boff,
    int* __restrict__ offs, int* __restrict__ endo,
    float* __restrict__ dinv, int* __restrict__ csr, int n)
{
  __shared__ int cnt_l[BN];
  __shared__ int tsum[256];
  __shared__ int lcur[BN];
  const int t = threadIdx.x;
  const int b = blockIdx.x;
  const int base = boff[b];
  const int end  = boff[b + 1];
  const int n0 = b << BIN_SHIFT;

  cnt_l[t] = 0; cnt_l[t + 256] = 0;
  __syncthreads();
  for (int i = base + t; i < end; i += 256)
    atomicAdd(&cnt_l[binned[i] & (BN - 1)], 1);
  __syncthreads();

  const int c0 = cnt_l[2 * t];
  const int c1 = cnt_l[2 * t + 1];
  const int s = c0 + c1;
  tsum[t] = s;
  __syncthreads();
  for (int d = 1; d < 256; d <<= 1) {
    int v = (t >= d) ? tsum[t - d] : 0;
    __syncthreads();
    tsum[t] += v;
    __syncthreads();
  }
  const int ex = tsum[t] - s;
  const int e0 = ex, e1 = ex + c0;
  const int g0 = n0 + 2 * t, g1 = g0 + 1;
  if (g0 < n) {
    offs[g0] = base + e0; endo[g0] = base + e1;
    dinv[g0] = rsqrtf((float)(c0 + 1));
  }
  if (g1 < n) {
    offs[g1] = base + e1; endo[g1] = base + e1 + c1;
    dinv[g1] = rsqrtf((float)(c1 + 1));
  }
  lcur[2 * t] = e0;
  lcur[2 * t + 1] = e1;
  __syncthreads();
  for (int i = base + t; i < end; i += 256) {
    int v = binned[i];
    int p = atomicAdd(&lcur[v & (BN - 1)], 1);
    csr[base + p] = v >> BIN_SHIFT;
  }
}

// ---------------- fallback path (N too big for bucket build) ---------------
__global__ __launch_bounds__(256) void k_count(const int* __restrict__ dst, int* cnt, int E) {
  int e = blockIdx.x * blockDim.x + threadIdx.x;
  if (e < E) atomicAdd(&cnt[dst[e]], 1);
}
__global__ __launch_bounds__(256) void k_dinv(const int* __restrict__ cnt, float* dinv, int n) {
  int i = blockIdx.x * blockDim.x + threadIdx.x;
  if (i < n) dinv[i] = rsqrtf((float)(cnt[i] + 1));
}
__global__ __launch_bounds__(256) void k_scan1(const int* __restrict__ cnt,
                                               int* offs, int* bsum, int n) {
  __shared__ int sh[256];
  const int t = threadIdx.x;
  const int base = blockIdx.x * 1024 + t * 4;
  int v0 = 0, v1 = 0, v2 = 0, v3 = 0;
  if (base + 0 < n) v0 = cnt[base + 0];
  if (base + 1 < n) v1 = cnt[base + 1];
  if (base + 2 < n) v2 = cnt[base + 2];
  if (base + 3 < n) v3 = cnt[base + 3];
  const int s = v0 + v1 + v2 + v3;
  sh[t] = s;
  __syncthreads();
  for (int d = 1; d < 256; d <<= 1) {
    int x = (t >= d) ? sh[t - d] : 0;
    __syncthreads();
    sh[t] += x;
    __syncthreads();
  }
  int o = sh[t] - s;
  if (t == 255) bsum[blockIdx.x] = sh[255];
  if (base + 0 < n) { offs[base + 0] = o; o += v0; }
  if (base + 1 < n) { offs[base + 1] = o; o += v1; }
  if (base + 2 < n) { offs[base + 2] = o; o += v2; }
  if (base + 3 < n) { offs[base + 3] = o; o += v3; }
}
__global__ __launch_bounds__(256) void k_scan2(int* bsum, int nb) {
  __shared__ int sh[256];
  const int t = threadIdx.x;
  int v = (t < nb) ? bsum[t] : 0;
  sh[t] = v;
  __syncthreads();
  for (int d = 1; d < 256; d <<= 1) {
    int x = (t >= d) ? sh[t - d] : 0;
    __syncthreads();
    sh[t] += x;
    __syncthreads();
  }
  if (t < nb) bsum[t] = sh[t] - v;
}
__global__ __launch_bounds__(256) void k_scan3(int* offs, const int* __restrict__ bsum,
                                               int* cursor, int n) {
  int i = blockIdx.x * blockDim.x + threadIdx.x;
  if (i < n) {
    int o = offs[i] + bsum[i >> 10];
    offs[i] = o;
    cursor[i] = o;
  }
}
__global__ __launch_bounds__(256) void k_fill(const int* __restrict__ src,
                                              const int* __restrict__ dst,
                                              int* cursor, int* csr, int E) {
  int e = blockIdx.x * blockDim.x + threadIdx.x;
  if (e < E) {
    int p = atomicAdd(&cursor[dst[e]], 1);
    csr[p] = src[e];
  }
}
// ---------------------------------------------------------------------------

// MFMA GEMM: Y[row][j] = (sum_k X[row][k]*W[k][j]) [*dinv[row]] [+bias[j]]
// Block = 64 rows, 4 waves. Xs/WTs bf16 in LDS, 16B-unit XOR swizzle.
// OUTBF: write to 4-slice layout hsS[col>>4][row][col&15] (nstride = N+1).
template<int K, int NOUT, bool SCALE, bool BIAS, bool OUTBF>
__global__ __launch_bounds__(256) void k_gemm(
    const float* __restrict__ X, const float* __restrict__ W,
    const float* __restrict__ dinv, const float* __restrict__ bias,
    void* __restrict__ Yv, int nrows, int nstride)
{
  constexpr int NCOL = (NOUT + 15) & ~15;
  constexpr int NT   = NCOL / 16;
  constexpr int KS   = K / 32;
  __shared__ __align__(16) unsigned short Xs[64 * K];
  __shared__ __align__(16) unsigned short WTs[NCOL * K];

  const int t = threadIdx.x;
  const int r0 = blockIdx.x * 64;

  if constexpr (NCOL != NOUT) {
    for (int i = t; i < (NCOL - NOUT) * K; i += 256)
      WTs[NOUT * K + i] = 0;
  }
  for (int idx = t; idx < K * NOUT; idx += 256) {
    int k = idx / NOUT, n = idx - k * NOUT;
    int u = (k >> 3) ^ (n & 7);
    WTs[n * K + u * 8 + (k & 7)] = f2bf(W[idx]);
  }
  for (int q = t; q < 16 * K; q += 256) {       // q = float4 index
    int row = q / (K / 4);
    int c4  = q - row * (K / 4);
    int gr  = r0 + row; if (gr >= nrows) gr = nrows - 1;
    float4 v = *(const float4*)&X[(size_t)gr * K + c4 * 4];
    int u = (c4 >> 1) ^ (row & 7);
    unsigned short* p = &Xs[row * K + u * 8 + (c4 & 1) * 4];
    p[0] = f2bf(v.x); p[1] = f2bf(v.y); p[2] = f2bf(v.z); p[3] = f2bf(v.w);
  }
  __syncthreads();

  const int wid  = t >> 6;
  const int lane = t & 63;
  const int l15  = lane & 15;
  const int kb   = lane >> 4;
  const int lrow = 16 * wid + l15;

  f32x4 acc[NT];
  #pragma unroll
  for (int j = 0; j < NT; ++j) { f32x4 z = {0.f, 0.f, 0.f, 0.f}; acc[j] = z; }

  #pragma unroll
  for (int ks = 0; ks < KS; ++ks) {
    const int ub = ks * 4 + kb;
    short8v a = *(const short8v*)&Xs[lrow * K + (ub ^ (lrow & 7)) * 8];
    #pragma unroll
    for (int j = 0; j < NT; ++j) {
      const int n = j * 16 + l15;
      short8v b = *(const short8v*)&WTs[n * K + (ub ^ (n & 7)) * 8];
      acc[j] = __builtin_amdgcn_mfma_f32_16x16x32_bf16(a, b, acc[j], 0, 0, 0);
    }
  }

  const int rbase = r0 + 16 * wid + kb * 4;
  #pragma unroll
  for (int r = 0; r < 4; ++r) {
    const int row = rbase + r;
    if (row >= nrows) continue;
    const float sc = SCALE ? dinv[row] : 1.f;
    #pragma unroll
    for (int j = 0; j < NT; ++j) {
      const int col = j * 16 + l15;
      if (col < NOUT) {
        float v = acc[j][r];
        if constexpr (SCALE) v *= sc;
        if constexpr (BIAS)  v += bias[col];
        if constexpr (OUTBF)
          ((unsigned short*)Yv)[((size_t)(col >> 4) * nstride + row) * 16 + (col & 15)] = f2bf(v);
        else
          ((float*)Yv)[(size_t)row * NOUT + col] = v;
      }
    }
  }
}

// Pull-aggregate + fused epilogue, feature-sliced with XCD affinity.
// One wave per (node, slice): 16 edge-groups x 4 lanes; lane loads 8B
// (4 bf16) of its group's edge row-slice -> 512B per wave-load.
// Edge index read DIRECTLY by the 4 consuming lanes (same-address
// broadcast, csr[beg + (lane>>2)]) -> no hot-loop shuffles.
// Epilogue: shfl_xor(4/8/16/32) reduce, lanes 0-3 write float4.
__global__ __launch_bounds__(256) void k_pull(
    const unsigned short* __restrict__ hsS, const int* __restrict__ csr,
    const int* __restrict__ offs, const int* __restrict__ endo,
    const float* __restrict__ dinv, const float* __restrict__ bias,
    float* __restrict__ out, int n)
{
  const int b     = blockIdx.x;
  const int slice = b & 3;
  const int wid   = threadIdx.x >> 6;
  const int lane  = threadIdx.x & 63;
  const int q     = lane & 3;            // feature quad (4 bf16 = 8B)
  const int eg    = lane >> 2;           // edge group 0..15
  const int node  = (b >> 2) * 4 + wid;
  if (node >= n) return;

  const unsigned short* hp = hsS + (size_t)slice * (n + 1) * 16;

  const int beg = offs[node];
  const int m   = endo[node] - beg;      // wave-uniform

  float a0 = 0.f, a1 = 0.f, a2 = 0.f, a3 = 0.f;

  for (int base = 0; base < m; base += 16) {
    const int e = base + eg;
    const int s = (e < m) ? csr[beg + e] : n;     // 4-lane broadcast read
    const uint2 u = *(const uint2*)&hp[(size_t)s * 16 + q * 4];
    a0 += bf2f((unsigned short)u.x); a1 += bf2f((unsigned short)(u.x >> 16));
    a2 += bf2f((unsigned short)u.y); a3 += bf2f((unsigned short)(u.y >> 16));
  }

  // reduce over the 16 edge groups (lane strides 4,8,16,32)
  #pragma unroll
  for (int d = 4; d <= 32; d <<= 1) {
    a0 += __shfl_xor(a0, d); a1 += __shfl_xor(a1, d);
    a2 += __shfl_xor(a2, d); a3 += __shfl_xor(a3, d);
  }

  if (lane < 4) {
    const uint2 u = *(const uint2*)&hp[(size_t)node * 16 + q * 4]; // self term
    a0 += bf2f((unsigned short)u.x); a1 += bf2f((unsigned short)(u.x >> 16));
    a2 += bf2f((unsigned short)u.y); a3 += bf2f((unsigned short)(u.y >> 16));
    const float dv = dinv[node];
    const float4 bb = *(const float4*)&bias[slice * 16 + q * 4];
    float4 o;
    o.x = fmaxf(fmaf(dv, a0, bb.x), 0.f);
    o.y = fmaxf(fmaf(dv, a1, bb.y), 0.f);
    o.z = fmaxf(fmaf(dv, a2, bb.z), 0.f);
    o.w = fmaxf(fmaf(dv, a3, bb.w), 0.f);
    *(float4*)&out[(size_t)node * 64 + slice * 16 + q * 4] = o;
  }
}

extern "C" void kernel_launch(void* const* d_in, const int* in_sizes, int n_in,
                              void* d_out, int out_size, void* d_ws, size_t ws_size,
                              hipStream_t stream) {
  const float* x  = (const float*)d_in[0];
  const int*   ei = (const int*)d_in[1];
  const float* W1 = (const float*)d_in[2];
  const float* b1 = (const float*)d_in[3];
  const float* W2 = (const float*)d_in[4];
  const float* b2 = (const float*)d_in[5];
  const float* Wh = (const float*)d_in[6];
  const float* bh = (const float*)d_in[7];
  float* out = (float*)d_out;

  const int N = in_sizes[0] / 128;
  const int E = in_sizes[1] / 2;
  const int* src = ei;
  const int* dst = ei + E;

  auto align_up = [](size_t v, size_t a) { return (v + a - 1) & ~(a - 1); };
  char* ws = (char*)d_ws;
  size_t off = 0;
  int*   cnt    = (int*)(ws + off);   off = align_up(off + (size_t)N * 4, 256);
  float* dinv   = (float*)(ws + off); off = align_up(off + (size_t)N * 4, 256);
  int*   offs   = (int*)(ws + off);   off = align_up(off + (size_t)N * 4, 256);
  int*   endo   = (int*)(ws + off);   off = align_up(off + (size_t)N * 4, 256);
  int*   bsum   = (int*)(ws + off);   off = align_up(off + 256 * 4, 256);
  int*   bhist  = (int*)(ws + off);   off = align_up(off + NB_MAX * 4, 256);
  int*   boff   = (int*)(ws + off);   off = align_up(off + (NB_MAX + 1) * 4, 256);
  int*   gcur   = (int*)(ws + off);   off = align_up(off + NB_MAX * 4, 256);
  int*   csr    = (int*)(ws + off);   off = align_up(off + (size_t)E * 4, 256);
  int*   binned = (int*)(ws + off);   off = align_up(off + (size_t)E * 4, 256);
  unsigned short* A = (unsigned short*)(ws + off);   // 4 slices x (N+1) x 16
  off = align_up(off + (size_t)(N + 1) * 64 * 2, 256);
  float* B      = (float*)(ws + off); off = align_up(off + (size_t)N * 64 * 4, 256);
  (void)ws_size;

  const int TB = 256;
  const int gN = (N + TB - 1) / TB;
  const int gE = (E + TB - 1) / TB;
  const int NBk = (N + BN - 1) >> BIN_SHIFT;      // buckets
  const int gGemm = (N + 63) / 64;
  const int gPull = ((N + 3) / 4) * 4;            // 4 nodes/block x 4 slices
  const int gBin  = (E + BIN_CHUNK - 1) / BIN_CHUNK;
  const int NS = N + 1;                           // slice stride (rows)

  k_zrow<<<1, 64, 0, stream>>>(A, N);             // sentinel zero rows

  if (NBk <= NB_MAX) {
    // ---- local CSR build (no scattered global atomics) ----
    k_zero <<<1, TB, 0, stream>>>(bhist, NBk);
    k_bhist<<<512, TB, 0, stream>>>(dst, bhist, E, NBk);
    k_bscan<<<1, TB, 0, stream>>>(bhist, boff, gcur, NBk, E);
    k_bin  <<<gBin, TB, 0, stream>>>(src, dst, gcur, binned, E);
    k_csr  <<<NBk, TB, 0, stream>>>(binned, boff, offs, endo, dinv, csr, N);
  } else {
    // ---- fallback: global count/scan/fill ----
    k_zero <<<gN, TB, 0, stream>>>(cnt, N);
    k_count<<<gE, TB, 0, stream>>>(dst, cnt, E);
    k_dinv <<<gN, TB, 0, stream>>>(cnt, dinv, N);
    const int nb1 = (N + 1023) / 1024;
    k_scan1<<<nb1, TB, 0, stream>>>(cnt, offs, bsum, N);
    k_scan2<<<1,  TB, 0, stream>>>(bsum, nb1);
    k_scan3<<<gN, TB, 0, stream>>>(offs, bsum, endo, N);
    k_fill <<<gE, TB, 0, stream>>>(src, dst, endo, csr, E);
  }

  // ---- layer 1 ----  A = hs1 (bf16, sliced) ; B = h1 (fp32)
  k_gemm<128, 64, true, false, true><<<gGemm, TB, 0, stream>>>(x, W1, dinv, nullptr, A, N, NS);
  k_pull<<<gPull, TB, 0, stream>>>(A, csr, offs, endo, dinv, b1, B, N);

  // ---- layer 2 ----  A = hs2 (bf16, sliced) ; B = h2 (fp32)
  k_gemm<64, 64, true, false, true><<<gGemm, TB, 0, stream>>>(B, W2, dinv, nullptr, A, N, NS);
  k_pull<<<gPull, TB, 0, stream>>>(A, csr, offs, endo, dinv, b2, B, N);

  // ---- head ----  out = h2 @ Wh + bh  (fp32)
  k_gemm<64, 40, false, true, false><<<gGemm, TB, 0, stream>>>(B, Wh, nullptr, bh, out, N, 0);
}

// Round 16
// 211.637 us; speedup vs baseline: 1.6042x; 1.6042x over previous
//
#include <hip/hip_runtime.h>
#include <hip/hip_bf16.h>

// ---------------------------------------------------------------------------
// GCN: h1 = relu(gcnconv(x, W1, b1)); h2 = relu(gcnconv(h1, W2, b2));
//      out = h2 @ Wh + bh
// gcnconv(x,W,b)[d] = dinv[d] * ( sum_{e: src->d} hs[src] + hs[d] ) + b
//   where hs = (x@W) * dinv[row],  dinv = rsqrt(indeg + 1)
// CSR build: bucket hist -> bucket scan -> bin-sort -> per-bucket LDS CSR.
// hs bf16 flat [N+1][64] (zero sentinel row N, written by gemm block 0).
// k_pull (round-12 optimum): 4 groups x 16 lanes, 4 edges per wave-load
// (512B/instr), 1 bpermute/edge, shfl_xor(16/32) reduce; NT hints on
// streaming csr/out to preserve L2 for the random hs gather.
// GEMM: MFMA 16x16x32 bf16, XOR-swizzled LDS, fp32 accumulate.
// ---------------------------------------------------------------------------

#define BIN_SHIFT 9
#define BN        (1 << BIN_SHIFT)     // 512 nodes per bucket
#define NB_MAX    256
#define BIN_CHUNK 4096                 // edges per k_bin block

typedef __attribute__((ext_vector_type(8))) short short8v;   // 8 bf16 (4 VGPR)
typedef __attribute__((ext_vector_type(4))) float f32x4;

__device__ __forceinline__ float bf2f(unsigned short u) {
  union { unsigned i; float f; } c; c.i = ((unsigned)u) << 16; return c.f;
}
__device__ __forceinline__ unsigned short f2bf(float f) {
  union { float f; unsigned i; } c; c.f = f;
  unsigned r = c.i + 0x7FFFu + ((c.i >> 16) & 1u);   // RNE
  return (unsigned short)(r >> 16);
}

__global__ __launch_bounds__(256) void k_zero(int* p, int n) {
  int i = blockIdx.x * blockDim.x + threadIdx.x;
  if (i < n) p[i] = 0;
}

// ---- bucket-level histogram (LDS pre-aggregated)
__global__ __launch_bounds__(256) void k_bhist(const int* __restrict__ dst,
                                               int* bhist, int E, int nb) {
  __shared__ int lh[NB_MAX];
  lh[threadIdx.x] = 0;
  __syncthreads();
  for (int i = blockIdx.x * 256 + threadIdx.x; i < E; i += gridDim.x * 256)
    atomicAdd(&lh[dst[i] >> BIN_SHIFT], 1);
  __syncthreads();
  int v = lh[threadIdx.x];
  if (threadIdx.x < nb && v) atomicAdd(&bhist[threadIdx.x], v);
}

// ---- scan bucket counts -> boff[nb+1], gcur
__global__ __launch_bounds__(256) void k_bscan(const int* __restrict__ bhist,
                                               int* boff, int* gcur, int nb, int E) {
  __shared__ int sh[256];
  const int t = threadIdx.x;
  int v = (t < nb) ? bhist[t] : 0;
  sh[t] = v;
  __syncthreads();
  for (int d = 1; d < 256; d <<= 1) {
    int x = (t >= d) ? sh[t - d] : 0;
    __syncthreads();
    sh[t] += x;
    __syncthreads();
  }
  if (t < nb) { int e = sh[t] - v; boff[t] = e; gcur[t] = e; }
  if (t == 0) boff[nb] = E;
}

// ---- split-sort edges into buckets by dst>>BIN_SHIFT (coalesced drain)
__global__ __launch_bounds__(256) void k_bin(
    const int* __restrict__ src, const int* __restrict__ dst,
    int* gcur, int* __restrict__ binned, int E)
{
  __shared__ int  hist[NB_MAX];
  __shared__ int  excl[NB_MAX];
  __shared__ int  lcur[NB_MAX];
  __shared__ int  gbase[NB_MAX];
  __shared__ int2 stage[BIN_CHUNK];

  const int t = threadIdx.x;
  const int base = blockIdx.x * BIN_CHUNK;
  const int m = min(BIN_CHUNK, E - base);

  int2 pr[BIN_CHUNK / 256];
  int nmine = 0;
  #pragma unroll
  for (int i = 0; i < BIN_CHUNK / 256; ++i) {
    int idx = t + 256 * i;
    if (idx < m) {
      pr[i].x = src[base + idx];
      pr[i].y = dst[base + idx];
      nmine = i + 1;
    }
  }

  hist[t] = 0;
  __syncthreads();
  #pragma unroll
  for (int i = 0; i < BIN_CHUNK / 256; ++i)
    if (i < nmine) atomicAdd(&hist[pr[i].y >> BIN_SHIFT], 1);
  __syncthreads();

  const int mycnt = hist[t];
  for (int d = 1; d < 256; d <<= 1) {
    int v = (t >= d) ? hist[t - d] : 0;
    __syncthreads();
    hist[t] += v;
    __syncthreads();
  }
  {
    int e = hist[t] - mycnt;
    excl[t] = e;
    lcur[t] = e;
    gbase[t] = mycnt ? atomicAdd(&gcur[t], mycnt) : 0;
  }
  __syncthreads();

  #pragma unroll
  for (int i = 0; i < BIN_CHUNK / 256; ++i)
    if (i < nmine) {
      int b = pr[i].y >> BIN_SHIFT;
      int p = atomicAdd(&lcur[b], 1);
      stage[p] = pr[i];
    }
  __syncthreads();

  for (int i = t; i < m; i += 256) {
    int2 pp = stage[i];
    int b = pp.y >> BIN_SHIFT;
    binned[gbase[b] + (i - excl[b])] =
        (pp.x << BIN_SHIFT) | (pp.y & (BN - 1));
  }
}

// ---- per-bucket CSR build: degree hist + scan + offs/endo/dinv + scatter
__global__ __launch_bounds__(256) void k_csr(
    const int* __restrict__ binned, const int* __restrict__ boff,
    int* __restrict__ offs, int* __restrict__ endo,
    float* __restrict__ dinv, int* __restrict__ csr, int n)
{
  __shared__ int cnt_l[BN];
  __shared__ int tsum[256];
  __shared__ int lcur[BN];
  const int t = threadIdx.x;
  const int b = blockIdx.x;
  const int base = boff[b];
  const int end  = boff[b + 1];
  const int n0 = b << BIN_SHIFT;

  cnt_l[t] = 0; cnt_l[t + 256] = 0;
  __syncthreads();
  for (int i = base + t; i < end; i += 256)
    atomicAdd(&cnt_l[binned[i] & (BN - 1)], 1);
  __syncthreads();

  const int c0 = cnt_l[2 * t];
  const int c1 = cnt_l[2 * t + 1];
  const int s = c0 + c1;
  tsum[t] = s;
  __syncthreads();
  for (int d = 1; d < 256; d <<= 1) {
    int v = (t >= d) ? tsum[t - d] : 0;
    __syncthreads();
    tsum[t] += v;
    __syncthreads();
  }
  const int ex = tsum[t] - s;
  const int e0 = ex, e1 = ex + c0;
  const int g0 = n0 + 2 * t, g1 = g0 + 1;
  if (g0 < n) {
    offs[g0] = base + e0; endo[g0] = base + e1;
    dinv[g0] = rsqrtf((float)(c0 + 1));
  }
  if (g1 < n) {
    offs[g1] = base + e1; endo[g1] = base + e1 + c1;
    dinv[g1] = rsqrtf((float)(c1 + 1));
  }
  lcur[2 * t] = e0;
  lcur[2 * t + 1] = e1;
  __syncthreads();
  for (int i = base + t; i < end; i += 256) {
    int v = binned[i];
    int p = atomicAdd(&lcur[v & (BN - 1)], 1);
    csr[base + p] = v >> BIN_SHIFT;
  }
}

// ---------------- fallback path (N too big for bucket build) ---------------
__global__ __launch_bounds__(256) void k_count(const int* __restrict__ dst, int* cnt, int E) {
  int e = blockIdx.x * blockDim.x + threadIdx.x;
  if (e < E) atomicAdd(&cnt[dst[e]], 1);
}
__global__ __launch_bounds__(256) void k_dinv(const int* __restrict__ cnt, float* dinv, int n) {
  int i = blockIdx.x * blockDim.x + threadIdx.x;
  if (i < n) dinv[i] = rsqrtf((float)(cnt[i] + 1));
}
__global__ __launch_bounds__(256) void k_scan1(const int* __restrict__ cnt,
                                               int* offs, int* bsum, int n) {
  __shared__ int sh[256];
  const int t = threadIdx.x;
  const int base = blockIdx.x * 1024 + t * 4;
  int v0 = 0, v1 = 0, v2 = 0, v3 = 0;
  if (base + 0 < n) v0 = cnt[base + 0];
  if (base + 1 < n) v1 = cnt[base + 1];
  if (base + 2 < n) v2 = cnt[base + 2];
  if (base + 3 < n) v3 = cnt[base + 3];
  const int s = v0 + v1 + v2 + v3;
  sh[t] = s;
  __syncthreads();
  for (int d = 1; d < 256; d <<= 1) {
    int x = (t >= d) ? sh[t - d] : 0;
    __syncthreads();
    sh[t] += x;
    __syncthreads();
  }
  int o = sh[t] - s;
  if (t == 255) bsum[blockIdx.x] = sh[255];
  if (base + 0 < n) { offs[base + 0] = o; o += v0; }
  if (base + 1 < n) { offs[base + 1] = o; o += v1; }
  if (base + 2 < n) { offs[base + 2] = o; o += v2; }
  if (base + 3 < n) { offs[base + 3] = o; o += v3; }
}
__global__ __launch_bounds__(256) void k_scan2(int* bsum, int nb) {
  __shared__ int sh[256];
  const int t = threadIdx.x;
  int v = (t < nb) ? bsum[t] : 0;
  sh[t] = v;
  __syncthreads();
  for (int d = 1; d < 256; d <<= 1) {
    int x = (t >= d) ? sh[t - d] : 0;
    __syncthreads();
    sh[t] += x;
    __syncthreads();
  }
  if (t < nb) bsum[t] = sh[t] - v;
}
__global__ __launch_bounds__(256) void k_scan3(int* offs, const int* __restrict__ bsum,
                                               int* cursor, int n) {
  int i = blockIdx.x * blockDim.x + threadIdx.x;
  if (i < n) {
    int o = offs[i] + bsum[i >> 10];
    offs[i] = o;
    cursor[i] = o;
  }
}
__global__ __launch_bounds__(256) void k_fill(const int* __restrict__ src,
                                              const int* __restrict__ dst,
                                              int* cursor, int* csr, int E) {
  int e = blockIdx.x * blockDim.x + threadIdx.x;
  if (e < E) {
    int p = atomicAdd(&cursor[dst[e]], 1);
    csr[p] = src[e];
  }
}
// ---------------------------------------------------------------------------

// MFMA GEMM: Y[row][j] = (sum_k X[row][k]*W[k][j]) [*dinv[row]] [+bias[j]]
// Block = 64 rows, 4 waves; wave w owns rows [16w,16w+16).
// Xs[64][K] bf16 and WTs[NCOL][K] bf16 in LDS, 16B-unit XOR swizzle
// u ^= (row&7). A: row=lane&15, k=(lane>>4)*8+i; B: col=lane&15, same k map
// (common k-bijection cancels). C/D: col=lane&15, row=(lane>>4)*4+reg.
// OUTBF: also zero the sentinel row nrows (block 0) for k_pull tails.
template<int K, int NOUT, bool SCALE, bool BIAS, bool OUTBF>
__global__ __launch_bounds__(256) void k_gemm(
    const float* __restrict__ X, const float* __restrict__ W,
    const float* __restrict__ dinv, const float* __restrict__ bias,
    void* __restrict__ Yv, int nrows)
{
  constexpr int NCOL = (NOUT + 15) & ~15;
  constexpr int NT   = NCOL / 16;         // col tiles per wave
  constexpr int KS   = K / 32;            // k-steps
  __shared__ __align__(16) unsigned short Xs[64 * K];
  __shared__ __align__(16) unsigned short WTs[NCOL * K];

  const int t = threadIdx.x;
  const int r0 = blockIdx.x * 64;

  if constexpr (OUTBF) {                  // sentinel zero row (folded k_zrow)
    if (blockIdx.x == 0 && t < 32)
      ((unsigned*)Yv)[(size_t)nrows * 32 + t] = 0u;
  }
  if constexpr (NCOL != NOUT) {
    for (int i = t; i < (NCOL - NOUT) * K; i += 256)
      WTs[NOUT * K + i] = 0;
  }
  // stage W^T bf16: W[k][n] fp32 -> WTs[n][ (k>>3 ^ n&7)*8 + (k&7) ]
  for (int idx = t; idx < K * NOUT; idx += 256) {
    int k = idx / NOUT, n = idx - k * NOUT;
    int u = (k >> 3) ^ (n & 7);
    WTs[n * K + u * 8 + (k & 7)] = f2bf(W[idx]);
  }
  // stage X slab bf16 (coalesced float4 reads, swizzled 8B writes)
  for (int q = t; q < 16 * K; q += 256) {       // q = float4 index
    int row = q / (K / 4);
    int c4  = q - row * (K / 4);
    int gr  = r0 + row; if (gr >= nrows) gr = nrows - 1;
    float4 v = *(const float4*)&X[(size_t)gr * K + c4 * 4];
    int u = (c4 >> 1) ^ (row & 7);
    unsigned short* p = &Xs[row * K + u * 8 + (c4 & 1) * 4];
    p[0] = f2bf(v.x); p[1] = f2bf(v.y); p[2] = f2bf(v.z); p[3] = f2bf(v.w);
  }
  __syncthreads();

  const int wid  = t >> 6;
  const int lane = t & 63;
  const int l15  = lane & 15;
  const int kb   = lane >> 4;             // k-block 0..3
  const int lrow = 16 * wid + l15;        // local A row

  f32x4 acc[NT];
  #pragma unroll
  for (int j = 0; j < NT; ++j) { f32x4 z = {0.f, 0.f, 0.f, 0.f}; acc[j] = z; }

  #pragma unroll
  for (int ks = 0; ks < KS; ++ks) {
    const int ub = ks * 4 + kb;           // linear 16B unit of this k-slice
    short8v a = *(const short8v*)&Xs[lrow * K + (ub ^ (lrow & 7)) * 8];
    #pragma unroll
    for (int j = 0; j < NT; ++j) {
      const int n = j * 16 + l15;
      short8v b = *(const short8v*)&WTs[n * K + (ub ^ (n & 7)) * 8];
      acc[j] = __builtin_amdgcn_mfma_f32_16x16x32_bf16(a, b, acc[j], 0, 0, 0);
    }
  }

  // epilogue: row = r0 + 16*wid + (lane>>4)*4 + reg, col = 16j + (lane&15)
  const int rbase = r0 + 16 * wid + kb * 4;
  #pragma unroll
  for (int r = 0; r < 4; ++r) {
    const int row = rbase + r;
    if (row >= nrows) continue;
    const float sc = SCALE ? dinv[row] : 1.f;
    #pragma unroll
    for (int j = 0; j < NT; ++j) {
      const int col = j * 16 + l15;
      if (col < NOUT) {
        float v = acc[j][r];
        if constexpr (SCALE) v *= sc;
        if constexpr (BIAS)  v += bias[col];
        if constexpr (OUTBF)
          ((unsigned short*)Yv)[(size_t)row * NOUT + col] = f2bf(v);
        else
          ((float*)Yv)[(size_t)row * NOUT + col] = v;
      }
    }
  }
}

// Pull-aggregate + fused epilogue (round-12 optimum shape). One wave per
// node. 4 groups x 16 lanes; group g handles edge 4i+g, lane fl loads
// features fl*4..fl*4+3 as uint2 (8B) -> 512B per wave-load instruction.
// Tail lanes use the sentinel zero-row index n. shfl_xor(16/32) reduce.
// NT hints: csr load + out store bypass-friendly (keep L2 for hs).
__global__ __launch_bounds__(256) void k_pull(
    const unsigned short* __restrict__ hs, const int* __restrict__ csr,
    const int* __restrict__ offs, const int* __restrict__ endo,
    const float* __restrict__ dinv, const float* __restrict__ bias,
    float* __restrict__ out, int n)
{
  const int node = blockIdx.x * 4 + (threadIdx.x >> 6);
  if (node >= n) return;
  const int lane = threadIdx.x & 63;
  const int g    = lane >> 4;
  const int fl   = lane & 15;

  const int beg = offs[node];
  const int m   = endo[node] - beg;
  const int mp  = (m + 3) & ~3;

  float a0 = 0.f, a1 = 0.f, a2 = 0.f, a3 = 0.f;

  for (int base = 0; base < mp; base += 64) {
    const int rem = mp - base;
    const int kk  = rem < 64 ? rem : 64;
    const int myidx = (base + lane < m)
        ? __builtin_nontemporal_load(&csr[beg + base + lane]) : n;
    const int nq = kk >> 2;
    #pragma unroll 4
    for (int i = 0; i < nq; ++i) {
      int s = __shfl(myidx, 4 * i + g);
      uint2 u = *(const uint2*)&hs[(size_t)s * 64 + fl * 4];
      a0 += bf2f((unsigned short)u.x); a1 += bf2f((unsigned short)(u.x >> 16));
      a2 += bf2f((unsigned short)u.y); a3 += bf2f((unsigned short)(u.y >> 16));
    }
  }

  a0 += __shfl_xor(a0, 16); a1 += __shfl_xor(a1, 16);
  a2 += __shfl_xor(a2, 16); a3 += __shfl_xor(a3, 16);
  a0 += __shfl_xor(a0, 32); a1 += __shfl_xor(a1, 32);
  a2 += __shfl_xor(a2, 32); a3 += __shfl_xor(a3, 32);

  if (lane < 16) {
    uint2 u = *(const uint2*)&hs[(size_t)node * 64 + fl * 4];   // self term
    a0 += bf2f((unsigned short)u.x); a1 += bf2f((unsigned short)(u.x >> 16));
    a2 += bf2f((unsigned short)u.y); a3 += bf2f((unsigned short)(u.y >> 16));
    const float dv = dinv[node];
    const float4 bb = *(const float4*)&bias[fl * 4];
    f32x4 o;
    o.x = fmaxf(fmaf(dv, a0, bb.x), 0.f);
    o.y = fmaxf(fmaf(dv, a1, bb.y), 0.f);
    o.z = fmaxf(fmaf(dv, a2, bb.z), 0.f);
    o.w = fmaxf(fmaf(dv, a3, bb.w), 0.f);
    __builtin_nontemporal_store(o, (f32x4*)&out[(size_t)node * 64 + fl * 4]);
  }
}

extern "C" void kernel_launch(void* const* d_in, const int* in_sizes, int n_in,
                              void* d_out, int out_size, void* d_ws, size_t ws_size,
                              hipStream_t stream) {
  const float* x  = (const float*)d_in[0];
  const int*   ei = (const int*)d_in[1];
  const float* W1 = (const float*)d_in[2];
  const float* b1 = (const float*)d_in[3];
  const float* W2 = (const float*)d_in[4];
  const float* b2 = (const float*)d_in[5];
  const float* Wh = (const float*)d_in[6];
  const float* bh = (const float*)d_in[7];
  float* out = (float*)d_out;

  const int N = in_sizes[0] / 128;
  const int E = in_sizes[1] / 2;
  const int* src = ei;
  const int* dst = ei + E;

  auto align_up = [](size_t v, size_t a) { return (v + a - 1) & ~(a - 1); };
  char* ws = (char*)d_ws;
  size_t off = 0;
  int*   cnt    = (int*)(ws + off);   off = align_up(off + (size_t)N * 4, 256);
  float* dinv   = (float*)(ws + off); off = align_up(off + (size_t)N * 4, 256);
  int*   offs   = (int*)(ws + off);   off = align_up(off + (size_t)N * 4, 256);
  int*   endo   = (int*)(ws + off);   off = align_up(off + (size_t)N * 4, 256);
  int*   bsum   = (int*)(ws + off);   off = align_up(off + 256 * 4, 256);
  int*   bhist  = (int*)(ws + off);   off = align_up(off + NB_MAX * 4, 256);
  int*   boff   = (int*)(ws + off);   off = align_up(off + (NB_MAX + 1) * 4, 256);
  int*   gcur   = (int*)(ws + off);   off = align_up(off + NB_MAX * 4, 256);
  int*   csr    = (int*)(ws + off);   off = align_up(off + (size_t)E * 4, 256);
  int*   binned = (int*)(ws + off);   off = align_up(off + (size_t)E * 4, 256);
  unsigned short* A = (unsigned short*)(ws + off);
  off = align_up(off + (size_t)(N + 1) * 64 * 2, 256);   // +1 sentinel zero row
  float* B      = (float*)(ws + off); off = align_up(off + (size_t)N * 64 * 4, 256);
  (void)ws_size;

  const int TB = 256;
  const int gN = (N + TB - 1) / TB;
  const int gE = (E + TB - 1) / TB;
  const int NBk = (N + BN - 1) >> BIN_SHIFT;      // buckets
  const int gGemm = (N + 63) / 64;
  const int gPull = (N + 3) / 4;
  const int gBin  = (E + BIN_CHUNK - 1) / BIN_CHUNK;

  if (NBk <= NB_MAX) {
    // ---- local CSR build (no scattered global atomics) ----
    k_zero <<<1, TB, 0, stream>>>(bhist, NBk);
    k_bhist<<<512, TB, 0, stream>>>(dst, bhist, E, NBk);
    k_bscan<<<1, TB, 0, stream>>>(bhist, boff, gcur, NBk, E);
    k_bin  <<<gBin, TB, 0, stream>>>(src, dst, gcur, binned, E);
    k_csr  <<<NBk, TB, 0, stream>>>(binned, boff, offs, endo, dinv, csr, N);
  } else {
    // ---- fallback: global count/scan/fill ----
    k_zero <<<gN, TB, 0, stream>>>(cnt, N);
    k_count<<<gE, TB, 0, stream>>>(dst, cnt, E);
    k_dinv <<<gN, TB, 0, stream>>>(cnt, dinv, N);
    const int nb1 = (N + 1023) / 1024;
    k_scan1<<<nb1, TB, 0, stream>>>(cnt, offs, bsum, N);
    k_scan2<<<1,  TB, 0, stream>>>(bsum, nb1);
    k_scan3<<<gN, TB, 0, stream>>>(offs, bsum, endo, N);
    k_fill <<<gE, TB, 0, stream>>>(src, dst, endo, csr, E);
  }

  // ---- layer 1 ----  A = hs1 (bf16) = (x@W1)*dinv ; B = h1 (fp32)
  k_gemm<128, 64, true, false, true><<<gGemm, TB, 0, stream>>>(x, W1, dinv, nullptr, A, N);
  k_pull<<<gPull, TB, 0, stream>>>(A, csr, offs, endo, dinv, b1, B, N);

  // ---- layer 2 ----  A = hs2 (bf16) = (h1@W2)*dinv ; B = h2 (fp32)
  k_gemm<64, 64, true, false, true><<<gGemm, TB, 0, stream>>>(B, W2, dinv, nullptr, A, N);
  k_pull<<<gPull, TB, 0, stream>>>(A, csr, offs, endo, dinv, b2, B, N);

  // ---- head ----  out = h2 @ Wh + bh  (fp32)
  k_gemm<64, 40, false, true, false><<<gGemm, TB, 0, stream>>>(B, Wh, nullptr, bh, out, N);
}

// Round 17
// 201.833 us; speedup vs baseline: 1.6822x; 1.0486x over previous
//
#include <hip/hip_runtime.h>
#include <hip/hip_bf16.h>

// ---------------------------------------------------------------------------
// GCN: h1 = relu(gcnconv(x, W1, b1)); h2 = relu(gcnconv(h1, W2, b2));
//      out = h2 @ Wh + bh
// gcnconv(x,W,b)[d] = dinv[d] * ( sum_{e: src->d} hs[src] + hs[d] ) + b
//   where hs = (x@W) * dinv[row],  dinv = rsqrt(indeg + 1)
// CSR build: bucket hist -> bucket scan -> bin-sort -> per-bucket LDS CSR.
// hs bf16 flat [N+1][64] (zero sentinel row N, written by gemm block 0).
// h1/h2 ALSO bf16 (RNE moved from gemm staging into pull store -> identical
// values, half the intermediate traffic). k_pull = round-12 optimum shape:
// 4 groups x 16 lanes, 4 edges per wave-load (512B/instr), shfl_xor reduce,
// plain (non-NT) loads/stores. GEMM: MFMA 16x16x32 bf16, XOR-swizzled LDS,
// fp32 accumulate; XBF path stages bf16 X without conversion.
// ---------------------------------------------------------------------------

#define BIN_SHIFT 9
#define BN        (1 << BIN_SHIFT)     // 512 nodes per bucket
#define NB_MAX    256
#define BIN_CHUNK 4096                 // edges per k_bin block

typedef __attribute__((ext_vector_type(8))) short short8v;   // 8 bf16 (4 VGPR)
typedef __attribute__((ext_vector_type(4))) float f32x4;

__device__ __forceinline__ float bf2f(unsigned short u) {
  union { unsigned i; float f; } c; c.i = ((unsigned)u) << 16; return c.f;
}
__device__ __forceinline__ unsigned short f2bf(float f) {
  union { float f; unsigned i; } c; c.f = f;
  unsigned r = c.i + 0x7FFFu + ((c.i >> 16) & 1u);   // RNE
  return (unsigned short)(r >> 16);
}

__global__ __launch_bounds__(256) void k_zero(int* p, int n) {
  int i = blockIdx.x * blockDim.x + threadIdx.x;
  if (i < n) p[i] = 0;
}

// ---- bucket-level histogram (LDS pre-aggregated)
__global__ __launch_bounds__(256) void k_bhist(const int* __restrict__ dst,
                                               int* bhist, int E, int nb) {
  __shared__ int lh[NB_MAX];
  lh[threadIdx.x] = 0;
  __syncthreads();
  for (int i = blockIdx.x * 256 + threadIdx.x; i < E; i += gridDim.x * 256)
    atomicAdd(&lh[dst[i] >> BIN_SHIFT], 1);
  __syncthreads();
  int v = lh[threadIdx.x];
  if (threadIdx.x < nb && v) atomicAdd(&bhist[threadIdx.x], v);
}

// ---- scan bucket counts -> boff[nb+1], gcur
__global__ __launch_bounds__(256) void k_bscan(const int* __restrict__ bhist,
                                               int* boff, int* gcur, int nb, int E) {
  __shared__ int sh[256];
  const int t = threadIdx.x;
  int v = (t < nb) ? bhist[t] : 0;
  sh[t] = v;
  __syncthreads();
  for (int d = 1; d < 256; d <<= 1) {
    int x = (t >= d) ? sh[t - d] : 0;
    __syncthreads();
    sh[t] += x;
    __syncthreads();
  }
  if (t < nb) { int e = sh[t] - v; boff[t] = e; gcur[t] = e; }
  if (t == 0) boff[nb] = E;
}

// ---- split-sort edges into buckets by dst>>BIN_SHIFT (coalesced drain)
__global__ __launch_bounds__(256) void k_bin(
    const int* __restrict__ src, const int* __restrict__ dst,
    int* gcur, int* __restrict__ binned, int E)
{
  __shared__ int  hist[NB_MAX];
  __shared__ int  excl[NB_MAX];
  __shared__ int  lcur[NB_MAX];
  __shared__ int  gbase[NB_MAX];
  __shared__ int2 stage[BIN_CHUNK];

  const int t = threadIdx.x;
  const int base = blockIdx.x * BIN_CHUNK;
  const int m = min(BIN_CHUNK, E - base);

  int2 pr[BIN_CHUNK / 256];
  int nmine = 0;
  #pragma unroll
  for (int i = 0; i < BIN_CHUNK / 256; ++i) {
    int idx = t + 256 * i;
    if (idx < m) {
      pr[i].x = src[base + idx];
      pr[i].y = dst[base + idx];
      nmine = i + 1;
    }
  }

  hist[t] = 0;
  __syncthreads();
  #pragma unroll
  for (int i = 0; i < BIN_CHUNK / 256; ++i)
    if (i < nmine) atomicAdd(&hist[pr[i].y >> BIN_SHIFT], 1);
  __syncthreads();

  const int mycnt = hist[t];
  for (int d = 1; d < 256; d <<= 1) {
    int v = (t >= d) ? hist[t - d] : 0;
    __syncthreads();
    hist[t] += v;
    __syncthreads();
  }
  {
    int e = hist[t] - mycnt;
    excl[t] = e;
    lcur[t] = e;
    gbase[t] = mycnt ? atomicAdd(&gcur[t], mycnt) : 0;
  }
  __syncthreads();

  #pragma unroll
  for (int i = 0; i < BIN_CHUNK / 256; ++i)
    if (i < nmine) {
      int b = pr[i].y >> BIN_SHIFT;
      int p = atomicAdd(&lcur[b], 1);
      stage[p] = pr[i];
    }
  __syncthreads();

  for (int i = t; i < m; i += 256) {
    int2 pp = stage[i];
    int b = pp.y >> BIN_SHIFT;
    binned[gbase[b] + (i - excl[b])] =
        (pp.x << BIN_SHIFT) | (pp.y & (BN - 1));
  }
}

// ---- per-bucket CSR build: degree hist + scan + offs/endo/dinv + scatter
__global__ __launch_bounds__(256) void k_csr(
    const int* __restrict__ binned, const int* __restrict__ boff,
    int* __restrict__ offs, int* __restrict__ endo,
    float* __restrict__ dinv, int* __restrict__ csr, int n)
{
  __shared__ int cnt_l[BN];
  __shared__ int tsum[256];
  __shared__ int lcur[BN];
  const int t = threadIdx.x;
  const int b = blockIdx.x;
  const int base = boff[b];
  const int end  = boff[b + 1];
  const int n0 = b << BIN_SHIFT;

  cnt_l[t] = 0; cnt_l[t + 256] = 0;
  __syncthreads();
  for (int i = base + t; i < end; i += 256)
    atomicAdd(&cnt_l[binned[i] & (BN - 1)], 1);
  __syncthreads();

  const int c0 = cnt_l[2 * t];
  const int c1 = cnt_l[2 * t + 1];
  const int s = c0 + c1;
  tsum[t] = s;
  __syncthreads();
  for (int d = 1; d < 256; d <<= 1) {
    int v = (t >= d) ? tsum[t - d] : 0;
    __syncthreads();
    tsum[t] += v;
    __syncthreads();
  }
  const int ex = tsum[t] - s;
  const int e0 = ex, e1 = ex + c0;
  const int g0 = n0 + 2 * t, g1 = g0 + 1;
  if (g0 < n) {
    offs[g0] = base + e0; endo[g0] = base + e1;
    dinv[g0] = rsqrtf((float)(c0 + 1));
  }
  if (g1 < n) {
    offs[g1] = base + e1; endo[g1] = base + e1 + c1;
    dinv[g1] = rsqrtf((float)(c1 + 1));
  }
  lcur[2 * t] = e0;
  lcur[2 * t + 1] = e1;
  __syncthreads();
  for (int i = base + t; i < end; i += 256) {
    int v = binned[i];
    int p = atomicAdd(&lcur[v & (BN - 1)], 1);
    csr[base + p] = v >> BIN_SHIFT;
  }
}

// ---------------- fallback path (N too big for bucket build) ---------------
__global__ __launch_bounds__(256) void k_count(const int* __restrict__ dst, int* cnt, int E) {
  int e = blockIdx.x * blockDim.x + threadIdx.x;
  if (e < E) atomicAdd(&cnt[dst[e]], 1);
}
__global__ __launch_bounds__(256) void k_dinv(const int* __restrict__ cnt, float* dinv, int n) {
  int i = blockIdx.x * blockDim.x + threadIdx.x;
  if (i < n) dinv[i] = rsqrtf((float)(cnt[i] + 1));
}
__global__ __launch_bounds__(256) void k_scan1(const int* __restrict__ cnt,
                                               int* offs, int* bsum, int n) {
  __shared__ int sh[256];
  const int t = threadIdx.x;
  const int base = blockIdx.x * 1024 + t * 4;
  int v0 = 0, v1 = 0, v2 = 0, v3 = 0;
  if (base + 0 < n) v0 = cnt[base + 0];
  if (base + 1 < n) v1 = cnt[base + 1];
  if (base + 2 < n) v2 = cnt[base + 2];
  if (base + 3 < n) v3 = cnt[base + 3];
  const int s = v0 + v1 + v2 + v3;
  sh[t] = s;
  __syncthreads();
  for (int d = 1; d < 256; d <<= 1) {
    int x = (t >= d) ? sh[t - d] : 0;
    __syncthreads();
    sh[t] += x;
    __syncthreads();
  }
  int o = sh[t] - s;
  if (t == 255) bsum[blockIdx.x] = sh[255];
  if (base + 0 < n) { offs[base + 0] = o; o += v0; }
  if (base + 1 < n) { offs[base + 1] = o; o += v1; }
  if (base + 2 < n) { offs[base + 2] = o; o += v2; }
  if (base + 3 < n) { offs[base + 3] = o; o += v3; }
}
__global__ __launch_bounds__(256) void k_scan2(int* bsum, int nb) {
  __shared__ int sh[256];
  const int t = threadIdx.x;
  int v = (t < nb) ? bsum[t] : 0;
  sh[t] = v;
  __syncthreads();
  for (int d = 1; d < 256; d <<= 1) {
    int x = (t >= d) ? sh[t - d] : 0;
    __syncthreads();
    sh[t] += x;
    __syncthreads();
  }
  if (t < nb) bsum[t] = sh[t] - v;
}
__global__ __launch_bounds__(256) void k_scan3(int* offs, const int* __restrict__ bsum,
                                               int* cursor, int n) {
  int i = blockIdx.x * blockDim.x + threadIdx.x;
  if (i < n) {
    int o = offs[i] + bsum[i >> 10];
    offs[i] = o;
    cursor[i] = o;
  }
}
__global__ __launch_bounds__(256) void k_fill(const int* __restrict__ src,
                                              const int* __restrict__ dst,
                                              int* cursor, int* csr, int E) {
  int e = blockIdx.x * blockDim.x + threadIdx.x;
  if (e < E) {
    int p = atomicAdd(&cursor[dst[e]], 1);
    csr[p] = src[e];
  }
}
// ---------------------------------------------------------------------------

// MFMA GEMM: Y[row][j] = (sum_k X[row][k]*W[k][j]) [*dinv[row]] [+bias[j]]
// Block = 64 rows, 4 waves; wave w owns rows [16w,16w+16).
// Xs[64][K] bf16 and WTs[NCOL][K] bf16 in LDS, 16B-unit XOR swizzle
// u ^= (row&7). A: row=lane&15, k=(lane>>4)*8+i; B: col=lane&15, same k map
// (common k-bijection cancels). C/D: col=lane&15, row=(lane>>4)*4+reg.
// XBF:   X is bf16 [nrows][K] -> staged with plain 16B copies.
// OUTBF: Y is bf16; block 0 zeros sentinel row nrows for k_pull tails.
template<int K, int NOUT, bool SCALE, bool BIAS, bool XBF, bool OUTBF>
__global__ __launch_bounds__(256) void k_gemm(
    const void* __restrict__ Xv, const float* __restrict__ W,
    const float* __restrict__ dinv, const float* __restrict__ bias,
    void* __restrict__ Yv, int nrows)
{
  constexpr int NCOL = (NOUT + 15) & ~15;
  constexpr int NT   = NCOL / 16;         // col tiles per wave
  constexpr int KS   = K / 32;            // k-steps
  __shared__ __align__(16) unsigned short Xs[64 * K];
  __shared__ __align__(16) unsigned short WTs[NCOL * K];

  const int t = threadIdx.x;
  const int r0 = blockIdx.x * 64;

  if constexpr (OUTBF) {                  // sentinel zero row (folded k_zrow)
    if (blockIdx.x == 0 && t < 32)
      ((unsigned*)Yv)[(size_t)nrows * 32 + t] = 0u;
  }
  if constexpr (NCOL != NOUT) {
    for (int i = t; i < (NCOL - NOUT) * K; i += 256)
      WTs[NOUT * K + i] = 0;
  }
  // stage W^T bf16: W[k][n] fp32 -> WTs[n][ (k>>3 ^ n&7)*8 + (k&7) ]
  for (int idx = t; idx < K * NOUT; idx += 256) {
    int k = idx / NOUT, n = idx - k * NOUT;
    int u = (k >> 3) ^ (n & 7);
    WTs[n * K + u * 8 + (k & 7)] = f2bf(W[idx]);
  }
  // stage X slab (coalesced reads, swizzled 16B-unit writes)
  if constexpr (XBF) {
    const unsigned short* Xb = (const unsigned short*)Xv;
    for (int q = t; q < 8 * K; q += 256) {      // q = 16B unit (8 bf16)
      int row = q / (K / 8);
      int c8  = q - row * (K / 8);
      int gr  = r0 + row; if (gr >= nrows) gr = nrows - 1;
      short8v v = *(const short8v*)&Xb[(size_t)gr * K + c8 * 8];
      int u = c8 ^ (row & 7);
      *(short8v*)&Xs[row * K + u * 8] = v;
    }
  } else {
    const float* X = (const float*)Xv;
    for (int q = t; q < 16 * K; q += 256) {     // q = float4 index
      int row = q / (K / 4);
      int c4  = q - row * (K / 4);
      int gr  = r0 + row; if (gr >= nrows) gr = nrows - 1;
      float4 v = *(const float4*)&X[(size_t)gr * K + c4 * 4];
      int u = (c4 >> 1) ^ (row & 7);
      unsigned short* p = &Xs[row * K + u * 8 + (c4 & 1) * 4];
      p[0] = f2bf(v.x); p[1] = f2bf(v.y); p[2] = f2bf(v.z); p[3] = f2bf(v.w);
    }
  }
  __syncthreads();

  const int wid  = t >> 6;
  const int lane = t & 63;
  const int l15  = lane & 15;
  const int kb   = lane >> 4;             // k-block 0..3
  const int lrow = 16 * wid + l15;        // local A row

  f32x4 acc[NT];
  #pragma unroll
  for (int j = 0; j < NT; ++j) { f32x4 z = {0.f, 0.f, 0.f, 0.f}; acc[j] = z; }

  #pragma unroll
  for (int ks = 0; ks < KS; ++ks) {
    const int ub = ks * 4 + kb;           // linear 16B unit of this k-slice
    short8v a = *(const short8v*)&Xs[lrow * K + (ub ^ (lrow & 7)) * 8];
    #pragma unroll
    for (int j = 0; j < NT; ++j) {
      const int n = j * 16 + l15;
      short8v b = *(const short8v*)&WTs[n * K + (ub ^ (n & 7)) * 8];
      acc[j] = __builtin_amdgcn_mfma_f32_16x16x32_bf16(a, b, acc[j], 0, 0, 0);
    }
  }

  // epilogue: row = r0 + 16*wid + (lane>>4)*4 + reg, col = 16j + (lane&15)
  const int rbase = r0 + 16 * wid + kb * 4;
  #pragma unroll
  for (int r = 0; r < 4; ++r) {
    const int row = rbase + r;
    if (row >= nrows) continue;
    const float sc = SCALE ? dinv[row] : 1.f;
    #pragma unroll
    for (int j = 0; j < NT; ++j) {
      const int col = j * 16 + l15;
      if (col < NOUT) {
        float v = acc[j][r];
        if constexpr (SCALE) v *= sc;
        if constexpr (BIAS)  v += bias[col];
        if constexpr (OUTBF)
          ((unsigned short*)Yv)[(size_t)row * NOUT + col] = f2bf(v);
        else
          ((float*)Yv)[(size_t)row * NOUT + col] = v;
      }
    }
  }
}

// Pull-aggregate + fused epilogue (round-12 optimum shape). One wave per
// node. 4 groups x 16 lanes; group g handles edge 4i+g, lane fl loads
// features fl*4..fl*4+3 as uint2 (8B) -> 512B per wave-load instruction.
// Tail lanes use the sentinel zero-row index n. shfl_xor(16/32) reduce.
// Output written as bf16 (RNE) -> h1/h2 bf16 (same values gemm would round).
__global__ __launch_bounds__(256) void k_pull(
    const unsigned short* __restrict__ hs, const int* __restrict__ csr,
    const int* __restrict__ offs, const int* __restrict__ endo,
    const float* __restrict__ dinv, const float* __restrict__ bias,
    unsigned short* __restrict__ out, int n)
{
  const int node = blockIdx.x * 4 + (threadIdx.x >> 6);
  if (node >= n) return;
  const int lane = threadIdx.x & 63;
  const int g    = lane >> 4;
  const int fl   = lane & 15;

  const int beg = offs[node];
  const int m   = endo[node] - beg;
  const int mp  = (m + 3) & ~3;

  float a0 = 0.f, a1 = 0.f, a2 = 0.f, a3 = 0.f;

  for (int base = 0; base < mp; base += 64) {
    const int rem = mp - base;
    const int kk  = rem < 64 ? rem : 64;
    const int myidx = (base + lane < m) ? csr[beg + base + lane] : n;
    const int nq = kk >> 2;
    #pragma unroll 4
    for (int i = 0; i < nq; ++i) {
      int s = __shfl(myidx, 4 * i + g);
      uint2 u = *(const uint2*)&hs[(size_t)s * 64 + fl * 4];
      a0 += bf2f((unsigned short)u.x); a1 += bf2f((unsigned short)(u.x >> 16));
      a2 += bf2f((unsigned short)u.y); a3 += bf2f((unsigned short)(u.y >> 16));
    }
  }

  a0 += __shfl_xor(a0, 16); a1 += __shfl_xor(a1, 16);
  a2 += __shfl_xor(a2, 16); a3 += __shfl_xor(a3, 16);
  a0 += __shfl_xor(a0, 32); a1 += __shfl_xor(a1, 32);
  a2 += __shfl_xor(a2, 32); a3 += __shfl_xor(a3, 32);

  if (lane < 16) {
    uint2 u = *(const uint2*)&hs[(size_t)node * 64 + fl * 4];   // self term
    a0 += bf2f((unsigned short)u.x); a1 += bf2f((unsigned short)(u.x >> 16));
    a2 += bf2f((unsigned short)u.y); a3 += bf2f((unsigned short)(u.y >> 16));
    const float dv = dinv[node];
    const float4 bb = *(const float4*)&bias[fl * 4];
    unsigned short r0b = f2bf(fmaxf(fmaf(dv, a0, bb.x), 0.f));
    unsigned short r1b = f2bf(fmaxf(fmaf(dv, a1, bb.y), 0.f));
    unsigned short r2b = f2bf(fmaxf(fmaf(dv, a2, bb.z), 0.f));
    unsigned short r3b = f2bf(fmaxf(fmaf(dv, a3, bb.w), 0.f));
    uint2 o;
    o.x = (unsigned)r0b | ((unsigned)r1b << 16);
    o.y = (unsigned)r2b | ((unsigned)r3b << 16);
    *(uint2*)&out[(size_t)node * 64 + fl * 4] = o;
  }
}

extern "C" void kernel_launch(void* const* d_in, const int* in_sizes, int n_in,
                              void* d_out, int out_size, void* d_ws, size_t ws_size,
                              hipStream_t stream) {
  const float* x  = (const float*)d_in[0];
  const int*   ei = (const int*)d_in[1];
  const float* W1 = (const float*)d_in[2];
  const float* b1 = (const float*)d_in[3];
  const float* W2 = (const float*)d_in[4];
  const float* b2 = (const float*)d_in[5];
  const float* Wh = (const float*)d_in[6];
  const float* bh = (const float*)d_in[7];
  float* out = (float*)d_out;

  const int N = in_sizes[0] / 128;
  const int E = in_sizes[1] / 2;
  const int* src = ei;
  const int* dst = ei + E;

  auto align_up = [](size_t v, size_t a) { return (v + a - 1) & ~(a - 1); };
  char* ws = (char*)d_ws;
  size_t off = 0;
  int*   cnt    = (int*)(ws + off);   off = align_up(off + (size_t)N * 4, 256);
  float* dinv   = (float*)(ws + off); off = align_up(off + (size_t)N * 4, 256);
  int*   offs   = (int*)(ws + off);   off = align_up(off + (size_t)N * 4, 256);
  int*   endo   = (int*)(ws + off);   off = align_up(off + (size_t)N * 4, 256);
  int*   bsum   = (int*)(ws + off);   off = align_up(off + 256 * 4, 256);
  int*   bhist  = (int*)(ws + off);   off = align_up(off + NB_MAX * 4, 256);
  int*   boff   = (int*)(ws + off);   off = align_up(off + (NB_MAX + 1) * 4, 256);
  int*   gcur   = (int*)(ws + off);   off = align_up(off + NB_MAX * 4, 256);
  int*   csr    = (int*)(ws + off);   off = align_up(off + (size_t)E * 4, 256);
  int*   binned = (int*)(ws + off);   off = align_up(off + (size_t)E * 4, 256);
  unsigned short* A = (unsigned short*)(ws + off);
  off = align_up(off + (size_t)(N + 1) * 64 * 2, 256);   // hs (+1 sentinel row)
  unsigned short* B = (unsigned short*)(ws + off);
  off = align_up(off + (size_t)N * 64 * 2, 256);         // h1/h2 (bf16)
  (void)ws_size;

  const int TB = 256;
  const int gN = (N + TB - 1) / TB;
  const int gE = (E + TB - 1) / TB;
  const int NBk = (N + BN - 1) >> BIN_SHIFT;      // buckets
  const int gGemm = (N + 63) / 64;
  const int gPull = (N + 3) / 4;
  const int gBin  = (E + BIN_CHUNK - 1) / BIN_CHUNK;

  if (NBk <= NB_MAX) {
    // ---- local CSR build (no scattered global atomics) ----
    k_zero <<<1, TB, 0, stream>>>(bhist, NBk);
    k_bhist<<<512, TB, 0, stream>>>(dst, bhist, E, NBk);
    k_bscan<<<1, TB, 0, stream>>>(bhist, boff, gcur, NBk, E);
    k_bin  <<<gBin, TB, 0, stream>>>(src, dst, gcur, binned, E);
    k_csr  <<<NBk, TB, 0, stream>>>(binned, boff, offs, endo, dinv, csr, N);
  } else {
    // ---- fallback: global count/scan/fill ----
    k_zero <<<gN, TB, 0, stream>>>(cnt, N);
    k_count<<<gE, TB, 0, stream>>>(dst, cnt, E);
    k_dinv <<<gN, TB, 0, stream>>>(cnt, dinv, N);
    const int nb1 = (N + 1023) / 1024;
    k_scan1<<<nb1, TB, 0, stream>>>(cnt, offs, bsum, N);
    k_scan2<<<1,  TB, 0, stream>>>(bsum, nb1);
    k_scan3<<<gN, TB, 0, stream>>>(offs, bsum, endo, N);
    k_fill <<<gE, TB, 0, stream>>>(src, dst, endo, csr, E);
  }

  // ---- layer 1 ----  A = hs1 (bf16) = (x@W1)*dinv ; B = h1 (bf16)
  k_gemm<128, 64, true, false, false, true><<<gGemm, TB, 0, stream>>>(x, W1, dinv, nullptr, A, N);
  k_pull<<<gPull, TB, 0, stream>>>(A, csr, offs, endo, dinv, b1, B, N);

  // ---- layer 2 ----  A = hs2 (bf16) = (h1@W2)*dinv ; B = h2 (bf16)
  k_gemm<64, 64, true, false, true, true><<<gGemm, TB, 0, stream>>>(B, W2, dinv, nullptr, A, N);
  k_pull<<<gPull, TB, 0, stream>>>(A, csr, offs, endo, dinv, b2, B, N);

  // ---- head ----  out = h2 @ Wh + bh  (fp32)
  k_gemm<64, 40, false, true, true, false><<<gGemm, TB, 0, stream>>>(B, Wh, nullptr, bh, out, N);
}